// Round 8
// baseline (1279.825 us; speedup 1.0000x reference)
//
#include <hip/hip_runtime.h>
#include <math.h>
#include <stdint.h>

// Problem constants
#define GS   29
#define GS2  841
#define NCP  24389            // 29^3 control points
#define DW   15
#define PP   225              // DW^2 displacements
#define CH   675              // PP*3 channels per control point
#define CHP  676              // padded row stride (4-elem aligned -> 8B-aligned half4)
#define CC   8                // feature channels
#define VV   64               // volume side
#define V3   262144           // 64^3
#define RP   237              // per-k LDS plane stride
#define COLS (GS2 * 169)      // z-smooth column chunks
#define NBT  1024             // tail grid: 4 blocks/CU x 256 CUs (co-residency guaranteed)

typedef __attribute__((ext_vector_type(8))) _Float16 half8;
typedef __attribute__((ext_vector_type(4))) _Float16 half4;
typedef __attribute__((ext_vector_type(2))) _Float16 half2v;

__device__ __forceinline__ float sv(int i) {
    return 0.4f * ((2.f * i + 1.f) * (1.f / 15.f) - 1.f);
}

// --- trilerp axis helpers ---
__device__ __forceinline__ void paxis(float pc, int& p0, float& wA, float& wB) {
    float iu = 0.5f * ((pc + 1.f) * (float)VV - 1.f);
    float u0f = floorf(iu);
    int u0 = (int)u0f;
    p0 = min(max(u0, 0), VV - 2);
    wA = (u0 < 0) ? 1.f : ((u0 >= VV - 1) ? 0.f : (1.f - (iu - u0f)));
    wB = 1.f - wA;
}
__device__ __forceinline__ void vaxis(float pc, int& c0, int& c1, float& w0, float& w1) {
    float iv = 0.5f * ((pc + 1.f) * (float)VV - 1.f);
    float v0f = floorf(iv);
    float fv = iv - v0f;
    int v0 = (int)v0f;
    c0 = min(max(v0, 0), VV - 1);
    c1 = min(max(v0 + 1, 0), VV - 1);
    w0 = 1.f - fv; w1 = fv;
}

__device__ __forceinline__ float sample_ssd(const _Float16* __restrict__ vol,
        int p0, float wAu, float wBu,
        int c0, int c1, float wv0, float wv1,
        int e0, int e1, float ww0, float ww1,
        half8 f8) {
    half8 acc = {0, 0, 0, 0, 0, 0, 0, 0};
#define PAIR(WC, VC, WGT) {                                               \
        float fA_ = (WGT) * wAu, fB_ = (WGT) * wBu;                       \
        _Float16 hA_ = (_Float16)fA_, hB_ = (_Float16)fB_;                \
        half8 hA8 = {hA_, hA_, hA_, hA_, hA_, hA_, hA_, hA_};             \
        half8 hB8 = {hB_, hB_, hB_, hB_, hB_, hB_, hB_, hB_};             \
        const _Float16* vp = vol + (size_t)((((WC) * VV) + (VC)) * VV + p0) * 8; \
        half8 lo = *(const half8*)vp;                                     \
        half8 hi = *(const half8*)(vp + 8);                               \
        acc += hA8 * lo;                                                  \
        acc += hB8 * hi;                                                  \
    }
    PAIR(e0, c0, ww0 * wv0)
    PAIR(e0, c1, ww0 * wv1)
    PAIR(e1, c0, ww1 * wv0)
    PAIR(e1, c1, ww1 * wv1)
#undef PAIR
    half8 d8 = f8 - acc;
#if __has_builtin(__builtin_amdgcn_fdot2)
    float ssd = 0.f;
#pragma unroll
    for (int j = 0; j < 4; j++) {
        half2v d2 = {d8[2 * j], d8[2 * j + 1]};
        ssd = __builtin_amdgcn_fdot2(d2, d2, ssd, false);
    }
    return ssd;
#else
    float ssd = 0.f;
#pragma unroll
    for (int c = 0; c < 8; c++) { float dc = (float)d8[c]; ssd = fmaf(dc, dc, ssd); }
    return ssd;
#endif
}

// feat50 (C,D,H,W) fp32 -> two fp16 channel-last volumes
__global__ __launch_bounds__(256) void make_vols(const float* __restrict__ in,
                                                 _Float16* __restrict__ volA,
                                                 _Float16* __restrict__ volB) {
    int v = blockIdx.x * 256 + threadIdx.x;
    if (v >= V3) return;
    int z = v >> 12, y = (v >> 6) & 63, x = v & 63;
    half8 h;
#pragma unroll
    for (int c = 0; c < CC; c++) h[c] = (_Float16)in[c * V3 + v];
    *(half8*)(volA + (size_t)v * 8) = h;
    *(half8*)(volB + (size_t)((((z << 6) | x) << 6) | y) * 8) = h;
}

// Block per n — unchanged from round 6 (verified, 122 us).
__global__ __launch_bounds__(256) void pdd_pool_n(const float* __restrict__ f00,
                                                  const _Float16* __restrict__ volA,
                                                  const _Float16* __restrict__ volB,
                                                  const float* __restrict__ grid,
                                                  const float* __restrict__ alpha,
                                                  _Float16* __restrict__ pdd,
                                                  _Float16* __restrict__ pool) {
    int n = blockIdx.x;
    int tid = threadIdx.x;
    __shared__ __align__(16) _Float16 fixh[8];
    __shared__ float rowp2[3][RP];
    __shared__ float smin[3 * 289];
    __shared__ float poolv2[3][RP];

    float gx = grid[n * 3 + 0], gy = grid[n * 3 + 1], gz = grid[n * 3 + 2];

    if (tid < 8) {
        float ix = 0.5f * ((gx + 1.f) * VV - 1.f);
        float iy = 0.5f * ((gy + 1.f) * VV - 1.f);
        float iz = 0.5f * ((gz + 1.f) * VV - 1.f);
        float x0f = floorf(ix), y0f = floorf(iy), z0f = floorf(iz);
        float fx = ix - x0f, fy = iy - y0f, fz = iz - z0f;
        int x0 = (int)x0f, y0 = (int)y0f, z0 = (int)z0f;
        const float* fc = f00 + tid * V3;
        float acc = 0.f;
        for (int dz = 0; dz < 2; dz++) {
            int zi = z0 + dz; float wz = dz ? fz : 1.f - fz;
            for (int dy = 0; dy < 2; dy++) {
                int yi = y0 + dy; float wy = dy ? fy : 1.f - fy;
                for (int dx = 0; dx < 2; dx++) {
                    int xi = x0 + dx; float wx = dx ? fx : 1.f - fx;
                    if (xi >= 0 && xi < VV && yi >= 0 && yi < VV && zi >= 0 && zi < VV)
                        acc += wx * wy * wz * fc[(zi * VV + yi) * VV + xi];
                }
            }
        }
        fixh[tid] = (_Float16)acc;
    }
    if (tid >= 225 && tid < 228) {
        int k = tid - 225;
        for (int q = PP; q < RP; q++) { rowp2[k][q] = 0.f; poolv2[k][q] = 0.f; }
    }
    __syncthreads();

    if (tid < PP) {
        int p = tid;
        int h_ = p / 15, w_ = p - 15 * h_;
        float A = sv(h_), B = sv(w_);
        half8 f8 = *(const half8*)fixh;
        float a0 = alpha[0], a1 = alpha[1];

        int pu01; float wAu01, wBu01; paxis(gx + B, pu01, wAu01, wBu01);
        int pu2 ; float wAu2 , wBu2 ; paxis(gy + B, pu2 , wAu2 , wBu2 );
        int va0, va1; float wva0, wva1; vaxis(gy + A, va0, va1, wva0, wva1);
        int wa0, wa1; float wwa0, wwa1; vaxis(gz + A, wa0, wa1, wwa0, wwa1);
        int zu0, zu1; float wzu0, wzu1; vaxis(gz, zu0, zu1, wzu0, wzu1);
        int vy0, vy1; float wvy0, wvy1; vaxis(gy, vy0, vy1, wvy0, wvy1);
        int vx0, vx1; float wvx0, wvx1; vaxis(gx, vx0, vx1, wvx0, wvx1);

        float s0 = sample_ssd(volA, pu01, wAu01, wBu01, va0, va1, wva0, wva1, zu0, zu1, wzu0, wzu1, f8);
        float s1 = sample_ssd(volA, pu01, wAu01, wBu01, vy0, vy1, wvy0, wvy1, wa0, wa1, wwa0, wwa1, f8);
        float s2 = sample_ssd(volB, pu2 , wAu2 , wBu2 , vx0, vx1, wvx0, wvx1, wa0, wa1, wwa0, wwa1, f8);
        rowp2[0][p] = a1 + a0 * s0;
        rowp2[1][p] = a1 + a0 * s1;
        rowp2[2][p] = a1 + a0 * s2;
    }
    __syncthreads();

    if (tid < 255) {
        int k = tid / 85, r = tid - 85 * k;
        int a = r / 5, bc = r - 5 * a;
        int b0 = bc * 4;
        int ra = max(a - 2, 0) * 15;
        int rb = min(max(a - 1, 0), 14) * 15;
        int rc = min(a, 14) * 15;
        float cm[6];
#pragma unroll
        for (int j = 0; j < 6; j++) {
            int cj = min(max(b0 - 2 + j, 0), 14);
            float m0 = rowp2[k][ra + cj];
            float m1 = rowp2[k][rb + cj];
            float m2 = rowp2[k][rc + cj];
            cm[j] = fminf(fminf(m0, m1), m2);
        }
#pragma unroll
        for (int o = 0; o < 4; o++) {
            int b = b0 + o;
            if (b < 17) smin[k * 289 + a * 17 + b] = fminf(fminf(cm[o], cm[o + 1]), cm[o + 2]);
        }
    }
    __syncthreads();

    if (tid < 180) {
        int k = tid / 60, r = tid - 60 * k;
        int h = r >> 2, wc = r & 3;
        int w0 = wc * 4;
        const float* S = smin + k * 289;
        float cs[6];
#pragma unroll
        for (int j = 0; j < 6; j++) {
            int cj = min(w0 + j, 16);
            cs[j] = S[h * 17 + cj] + S[(h + 1) * 17 + cj] + S[(h + 2) * 17 + cj];
        }
#pragma unroll
        for (int o = 0; o < 4; o++) {
            int w = w0 + o;
            if (w < 15) poolv2[k][h * 15 + w] = (cs[o] + cs[o + 1] + cs[o + 2]) * (1.f / 9.f);
        }
    }
    __syncthreads();

    if (tid < 169) {
        int c0 = tid * 4;
        half4 hp, hq;
#pragma unroll
        for (int j = 0; j < 4; j++) {
            int i = c0 + j;
            int p = i / 3, k = i - 3 * p;
            hp[j] = (_Float16)rowp2[k][p];
            hq[j] = (_Float16)poolv2[k][p];
        }
        *(half4*)(pdd + (size_t)n * CHP + c0) = hp;
        *(half4*)(pool + (size_t)n * CHP + c0) = hq;
    }
}

// ---------------- fused tail, normal launch + manual grid barrier ----------------

// Device-scope grid barrier. Slot `idx` used once per launch; counters zeroed
// by hipMemsetAsync before the kernel. __threadfence() on gfx950 emits the
// cross-XCD L2 writeback/invalidate needed for inter-block visibility.
__device__ __forceinline__ void gridbar(unsigned* bar, int idx, unsigned nb) {
    __syncthreads();
    __threadfence();                       // release: publish this block's writes
    if (threadIdx.x == 0) {
        unsigned* c = bar + idx * 16;      // 64B-separated slots
        atomicAdd(c, 1u);
        while (__hip_atomic_load(c, __ATOMIC_ACQUIRE, __HIP_MEMORY_SCOPE_AGENT) < nb) {
            __builtin_amdgcn_s_sleep(8);
        }
    }
    __syncthreads();
    __threadfence();                       // acquire: invalidate stale caches
}

__device__ __forceinline__ void zsmooth_phase(const _Float16* __restrict__ in,
                                              _Float16* __restrict__ out, int nthreads) {
    const size_t ZS = (size_t)GS2 * CHP;
    const float w0 = 1.f / 9.f, w1 = 2.f / 9.f, w2 = 3.f / 9.f;
    const int TOT = COLS * 4;
    for (int w = blockIdx.x * 256 + threadIdx.x; w < TOT; w += nthreads) {
        int seg = w / COLS; int id = w - seg * COLS;
        int z0 = seg * 8;
        int z1 = min(z0 + 8, GS);
        int row = id / 169, c4 = id - 169 * row;
        size_t base = (size_t)row * CHP + c4 * 4;

        float v0[4], v1[4], v2[4], v3[4], v4[4];
        {
            int za = max(z0 - 2, 0), zb = max(z0 - 1, 0);
            int zd = min(z0 + 1, GS - 1), ze = min(z0 + 2, GS - 1);
            half4 ha = *(const half4*)(in + base + (size_t)za * ZS);
            half4 hb = *(const half4*)(in + base + (size_t)zb * ZS);
            half4 hc = *(const half4*)(in + base + (size_t)z0 * ZS);
            half4 hd = *(const half4*)(in + base + (size_t)zd * ZS);
            half4 he = *(const half4*)(in + base + (size_t)ze * ZS);
#pragma unroll
            for (int j = 0; j < 4; j++) {
                v0[j] = (float)ha[j]; v1[j] = (float)hb[j]; v2[j] = (float)hc[j];
                v3[j] = (float)hd[j]; v4[j] = (float)he[j];
            }
        }
        for (int z = z0; z < z1; z++) {
            half4 o;
#pragma unroll
            for (int j = 0; j < 4; j++)
                o[j] = (_Float16)(w0 * (v0[j] + v4[j]) + w1 * (v1[j] + v3[j]) + w2 * v2[j]);
            *(half4*)(out + base + (size_t)z * ZS) = o;
            int zn = min(z + 3, GS - 1);
            half4 hn = *(const half4*)(in + base + (size_t)zn * ZS);
#pragma unroll
            for (int j = 0; j < 4; j++) {
                v0[j] = v1[j]; v1[j] = v2[j]; v2[j] = v3[j]; v3[j] = v4[j];
                v4[j] = (float)hn[j];
            }
        }
    }
}

__global__ __launch_bounds__(256, 4) void tail_fused(_Float16* __restrict__ pool1,
                                                     const _Float16* __restrict__ pddb,
                                                     _Float16* __restrict__ tmp,
                                                     const float* __restrict__ alpha,
                                                     float* __restrict__ ca,
                                                     float* __restrict__ soft,
                                                     float* __restrict__ pred,
                                                     unsigned* __restrict__ bar) {
    const int NB = NBT;
    const int NT = NB * 256;
    int tid = threadIdx.x;

    __shared__ float rowp2[3][RP];
    __shared__ float smin[3 * 289];
    __shared__ float poolv2[3][RP];
    __shared__ float partial[3][3];

    // Phase A: z-smooth pool1 -> tmp
    zsmooth_phase(pool1, tmp, NT);
    gridbar(bar, 0, NB);

    // Phase B: per-n y-smooth + cost + min3x3 + avg3x3 -> pool2 (into pool1)
    float a2 = alpha[2], a3 = alpha[3], a4 = alpha[4];
    for (int n = blockIdx.x; n < NCP; n += NB) {
        int x = n % GS; int zy = n / GS; int y = zy % GS; int z = zy / GS;

        if (tid >= 225 && tid < 228) {
            int k = tid - 225;
            for (int q = PP; q < RP; q++) { rowp2[k][q] = 0.f; poolv2[k][q] = 0.f; }
        }
        if (tid < 169) {
            int c0 = tid * 4;
            float s0 = 0.f, s1 = 0.f, s2 = 0.f, s3 = 0.f;
#pragma unroll
            for (int dy = 0; dy < 5; dy++) {
                int yy = min(max(y + dy - 2, 0), GS - 1);
                size_t off = ((size_t)(z * GS + yy) * GS + x) * CHP + c0;
                float w = (3.f - fabsf((float)dy - 2.f)) * (1.f / 9.f);
                half4 hv = *(const half4*)(tmp + off);
                s0 = fmaf(w, (float)hv[0], s0);
                s1 = fmaf(w, (float)hv[1], s1);
                s2 = fmaf(w, (float)hv[2], s2);
                s3 = fmaf(w, (float)hv[3], s3);
            }
            half4 pv = *(const half4*)(pddb + (size_t)n * CHP + c0);
            float sm[4] = {s0, s1, s2, s3};
#pragma unroll
            for (int j = 0; j < 4; j++) {
                int i = c0 + j;
                if (i < CH) {
                    int p = i / 3, k = i - 3 * p;
                    rowp2[k][p] = a4 + a2 * (float)pv[j] + a3 * sm[j];
                }
            }
        }
        __syncthreads();

        if (tid < 255) {
            int k = tid / 85, r = tid - 85 * k;
            int a = r / 5, bc = r - 5 * a;
            int b0 = bc * 4;
            int ra = max(a - 2, 0) * 15;
            int rb = min(max(a - 1, 0), 14) * 15;
            int rc = min(a, 14) * 15;
            float cm[6];
#pragma unroll
            for (int j = 0; j < 6; j++) {
                int cj = min(max(b0 - 2 + j, 0), 14);
                float m0 = rowp2[k][ra + cj];
                float m1 = rowp2[k][rb + cj];
                float m2 = rowp2[k][rc + cj];
                cm[j] = fminf(fminf(m0, m1), m2);
            }
#pragma unroll
            for (int o = 0; o < 4; o++) {
                int b = b0 + o;
                if (b < 17) smin[k * 289 + a * 17 + b] = fminf(fminf(cm[o], cm[o + 1]), cm[o + 2]);
            }
        }
        __syncthreads();

        if (tid < 180) {
            int k = tid / 60, r = tid - 60 * k;
            int h = r >> 2, wc = r & 3;
            int w0 = wc * 4;
            const float* S = smin + k * 289;
            float cs[6];
#pragma unroll
            for (int j = 0; j < 6; j++) {
                int cj = min(w0 + j, 16);
                cs[j] = S[h * 17 + cj] + S[(h + 1) * 17 + cj] + S[(h + 2) * 17 + cj];
            }
#pragma unroll
            for (int o = 0; o < 4; o++) {
                int w = w0 + o;
                if (w < 15) poolv2[k][h * 15 + w] = (cs[o] + cs[o + 1] + cs[o + 2]) * (1.f / 9.f);
            }
        }
        __syncthreads();

        if (tid < 169) {
            int c0 = tid * 4;
            half4 hq;
#pragma unroll
            for (int j = 0; j < 4; j++) {
                int i = c0 + j;
                int p = i / 3, k = i - 3 * p;
                hq[j] = (_Float16)poolv2[k][p];
            }
            *(half4*)(pool1 + (size_t)n * CHP + c0) = hq;
        }
        __syncthreads();
    }
    gridbar(bar, 1, NB);

    // Phase C: z-smooth pool2 -> tmp
    zsmooth_phase(pool1, tmp, NT);
    gridbar(bar, 2, NB);

    // Phase D: per-n y-smooth -> cost_avg, softmax + pred
    float a5 = alpha[5];
    float* vals = &rowp2[0][0];                 // 711 floats >= CHP
    int wave = tid >> 6, lane = tid & 63;
    for (int n = blockIdx.x; n < NCP; n += NB) {
        int x = n % GS; int zy = n / GS; int y = zy % GS; int z = zy / GS;

        if (tid < 169) {
            int c0 = tid * 4;
            float s0 = 0.f, s1 = 0.f, s2 = 0.f, s3 = 0.f;
#pragma unroll
            for (int dy = 0; dy < 5; dy++) {
                int yy = min(max(y + dy - 2, 0), GS - 1);
                size_t off = ((size_t)(z * GS + yy) * GS + x) * CHP + c0;
                float w = (3.f - fabsf((float)dy - 2.f)) * (1.f / 9.f);
                half4 hv = *(const half4*)(tmp + off);
                s0 = fmaf(w, (float)hv[0], s0);
                s1 = fmaf(w, (float)hv[1], s1);
                s2 = fmaf(w, (float)hv[2], s2);
                s3 = fmaf(w, (float)hv[3], s3);
            }
            vals[c0 + 0] = s0;
            vals[c0 + 1] = s1;
            vals[c0 + 2] = s2;
            vals[c0 + 3] = s3;
        }
        __syncthreads();

        for (int i = tid; i < CH; i += 256) ca[(size_t)n * CH + i] = vals[i];
        __syncthreads();

        if (wave < 3) {
            int k = wave;
            float v[4], e[4];
            float m = -1e30f;
#pragma unroll
            for (int j = 0; j < 4; j++) {
                int p = lane + 64 * j;
                v[j] = (p < PP) ? -a5 * vals[p * 3 + k] : -1e30f;
                m = fmaxf(m, v[j]);
            }
#pragma unroll
            for (int o = 32; o > 0; o >>= 1) m = fmaxf(m, __shfl_xor(m, o));
            float sum = 0.f;
#pragma unroll
            for (int j = 0; j < 4; j++) {
                int p = lane + 64 * j;
                e[j] = (p < PP) ? __expf(v[j] - m) : 0.f;
                sum += e[j];
            }
#pragma unroll
            for (int o = 32; o > 0; o >>= 1) sum += __shfl_xor(sum, o);
            float inv = 1.f / sum;
            float px = 0.f, py = 0.f, pz = 0.f;
#pragma unroll
            for (int j = 0; j < 4; j++) {
                int p = lane + 64 * j;
                if (p < PP) {
                    float s = e[j] * inv;
                    vals[p * 3 + k] = s;
                    int h_ = p / 15, w_ = p - 15 * h_;
                    float A = sv(h_), B = sv(w_);
                    if (k == 0)      { px += s * B; py += s * A; }
                    else if (k == 1) { px += s * B; pz += s * A; }
                    else             { py += s * B; pz += s * A; }
                }
            }
#pragma unroll
            for (int o = 32; o > 0; o >>= 1) {
                px += __shfl_xor(px, o);
                py += __shfl_xor(py, o);
                pz += __shfl_xor(pz, o);
            }
            if (lane == 0) { partial[k][0] = px; partial[k][1] = py; partial[k][2] = pz; }
        }
        __syncthreads();
        if (tid < 3) pred[(size_t)n * 3 + tid] = 0.5f * (partial[0][tid] + partial[1][tid] + partial[2][tid]);
        for (int i = tid; i < CH; i += 256) soft[(size_t)n * CH + i] = vals[i];
        __syncthreads();
    }
}

extern "C" void kernel_launch(void* const* d_in, const int* in_sizes, int n_in,
                              void* d_out, int out_size, void* d_ws, size_t ws_size,
                              hipStream_t stream) {
    const float* f00   = (const float*)d_in[0];
    const float* f50   = (const float*)d_in[1];
    const float* grid  = (const float*)d_in[3];
    const float* alpha = (const float*)d_in[5];

    float* out0 = (float*)d_out;                   // cost_soft  (N*675)
    float* out1 = out0 + (size_t)NCP * CH;         // pred_xyz   (N*3)
    float* out2 = out1 + (size_t)NCP * 3;          // cost_avg   (N*675)

    char* ws = (char*)d_ws;
    _Float16* volA = (_Float16*)ws;                          // 4MB
    _Float16* volB = volA + (size_t)V3 * 8;                  // 4MB
    _Float16* H0 = volB + (size_t)V3 * 8;                    // N*CHP fp16 (pdd)
    _Float16* H1 = H0 + (size_t)NCP * CHP;                   // N*CHP fp16 (pool1 -> pool2)
    _Float16* H2 = H1 + (size_t)NCP * CHP;                   // N*CHP fp16 (z-smooth tmp)
    // barrier counters: 256B, 256-aligned, after H2
    unsigned* bar = (unsigned*)(((uintptr_t)(H2 + (size_t)NCP * CHP) + 255) & ~(uintptr_t)255);

    hipMemsetAsync(bar, 0, 256, stream);

    make_vols<<<(V3 + 255) / 256, 256, 0, stream>>>(f50, volA, volB);

    pdd_pool_n<<<NCP, 256, 0, stream>>>(f00, volA, volB, grid, alpha, H0, H1);

    // fused tail: zsmooth -> cost+pool2 -> zsmooth -> smooth+softmax
    tail_fused<<<NBT, 256, 0, stream>>>(H1, H0, H2, alpha, out2, out0, out1, bar);
}

// Round 9
// 469.859 us; speedup vs baseline: 2.7238x; 2.7238x over previous
//
#include <hip/hip_runtime.h>
#include <math.h>

// Problem constants
#define GS   29
#define GS2  841
#define NCP  24389            // 29^3 control points
#define DW   15
#define PP   225              // DW^2 displacements
#define CH   675              // PP*3 channels per control point
#define CHP  676              // padded row stride (4-elem aligned -> 8B-aligned half4)
#define CC   8                // feature channels
#define VV   64               // volume side
#define V3   262144           // 64^3
#define RP   237              // per-k LDS plane stride
#define NXCD 8

typedef __attribute__((ext_vector_type(8))) _Float16 half8;
typedef __attribute__((ext_vector_type(4))) _Float16 half4;
typedef __attribute__((ext_vector_type(2))) _Float16 half2v;

__device__ __forceinline__ float sv(int i) {
    // DR * ((2i+1)/DW - 1)
    return 0.4f * ((2.f * i + 1.f) * (1.f / 15.f) - 1.f);
}

// Bijective XCD-chunked swizzle (m204): consecutive-dispatch blocks (round-robin
// across XCDs) map to contiguous n-ranges per XCD -> L2 locality for shared rows.
__device__ __forceinline__ int xcd_swz(int orig, int nwg) {
    int q = nwg / NXCD, r = nwg - q * NXCD;
    int xcd = orig % NXCD, idx = orig / NXCD;
    int base = (xcd < r) ? xcd * (q + 1) : r * (q + 1) + (xcd - r) * q;
    return base + idx;
}

// --- trilerp axis helpers ---
__device__ __forceinline__ void paxis(float pc, int& p0, float& wA, float& wB) {
    float iu = 0.5f * ((pc + 1.f) * (float)VV - 1.f);
    float u0f = floorf(iu);
    int u0 = (int)u0f;
    p0 = min(max(u0, 0), VV - 2);
    wA = (u0 < 0) ? 1.f : ((u0 >= VV - 1) ? 0.f : (1.f - (iu - u0f)));
    wB = 1.f - wA;
}
__device__ __forceinline__ void vaxis(float pc, int& c0, int& c1, float& w0, float& w1) {
    float iv = 0.5f * ((pc + 1.f) * (float)VV - 1.f);
    float v0f = floorf(iv);
    float fv = iv - v0f;
    int v0 = (int)v0f;
    c0 = min(max(v0, 0), VV - 1);
    c1 = min(max(v0 + 1, 0), VV - 1);
    w0 = 1.f - fv; w1 = fv;
}

__device__ __forceinline__ float sample_ssd(const _Float16* __restrict__ vol,
        int p0, float wAu, float wBu,
        int c0, int c1, float wv0, float wv1,
        int e0, int e1, float ww0, float ww1,
        half8 f8) {
    half8 acc = {0, 0, 0, 0, 0, 0, 0, 0};
#define PAIR(WC, VC, WGT) {                                               \
        float fA_ = (WGT) * wAu, fB_ = (WGT) * wBu;                       \
        _Float16 hA_ = (_Float16)fA_, hB_ = (_Float16)fB_;                \
        half8 hA8 = {hA_, hA_, hA_, hA_, hA_, hA_, hA_, hA_};             \
        half8 hB8 = {hB_, hB_, hB_, hB_, hB_, hB_, hB_, hB_};             \
        const _Float16* vp = vol + (size_t)((((WC) * VV) + (VC)) * VV + p0) * 8; \
        half8 lo = *(const half8*)vp;                                     \
        half8 hi = *(const half8*)(vp + 8);                               \
        acc += hA8 * lo;                                                  \
        acc += hB8 * hi;                                                  \
    }
    PAIR(e0, c0, ww0 * wv0)
    PAIR(e0, c1, ww0 * wv1)
    PAIR(e1, c0, ww1 * wv0)
    PAIR(e1, c1, ww1 * wv1)
#undef PAIR
    half8 d8 = f8 - acc;
#if __has_builtin(__builtin_amdgcn_fdot2)
    float ssd = 0.f;
#pragma unroll
    for (int j = 0; j < 4; j++) {
        half2v d2 = {d8[2 * j], d8[2 * j + 1]};
        ssd = __builtin_amdgcn_fdot2(d2, d2, ssd, false);
    }
    return ssd;
#else
    float ssd = 0.f;
#pragma unroll
    for (int c = 0; c < 8; c++) { float dc = (float)d8[c]; ssd = fmaf(dc, dc, ssd); }
    return ssd;
#endif
}

// feat50 (C,D,H,W) fp32 -> two fp16 channel-last volumes
__global__ __launch_bounds__(256) void make_vols(const float* __restrict__ in,
                                                 _Float16* __restrict__ volA,
                                                 _Float16* __restrict__ volB) {
    int v = blockIdx.x * 256 + threadIdx.x;
    if (v >= V3) return;
    int z = v >> 12, y = (v >> 6) & 63, x = v & 63;
    half8 h;
#pragma unroll
    for (int c = 0; c < CC; c++) h[c] = (_Float16)in[c * V3 + v];
    *(half8*)(volA + (size_t)v * 8) = h;
    *(half8*)(volB + (size_t)((((z << 6) | x) << 6) | y) * 8) = h;
}

// Block per n (XCD-swizzled). Round-6 body (verified 122 us).
__global__ __launch_bounds__(256) void pdd_pool_n(const float* __restrict__ f00,
                                                  const _Float16* __restrict__ volA,
                                                  const _Float16* __restrict__ volB,
                                                  const float* __restrict__ grid,
                                                  const float* __restrict__ alpha,
                                                  _Float16* __restrict__ pdd,
                                                  _Float16* __restrict__ pool) {
    int n = xcd_swz(blockIdx.x, NCP);
    int tid = threadIdx.x;
    __shared__ __align__(16) _Float16 fixh[8];
    __shared__ float rowp2[3][RP];
    __shared__ float smin[3 * 289];
    __shared__ float poolv2[3][RP];

    float gx = grid[n * 3 + 0], gy = grid[n * 3 + 1], gz = grid[n * 3 + 2];

    if (tid < 8) {
        float ix = 0.5f * ((gx + 1.f) * VV - 1.f);
        float iy = 0.5f * ((gy + 1.f) * VV - 1.f);
        float iz = 0.5f * ((gz + 1.f) * VV - 1.f);
        float x0f = floorf(ix), y0f = floorf(iy), z0f = floorf(iz);
        float fx = ix - x0f, fy = iy - y0f, fz = iz - z0f;
        int x0 = (int)x0f, y0 = (int)y0f, z0 = (int)z0f;
        const float* fc = f00 + tid * V3;
        float acc = 0.f;
        for (int dz = 0; dz < 2; dz++) {
            int zi = z0 + dz; float wz = dz ? fz : 1.f - fz;
            for (int dy = 0; dy < 2; dy++) {
                int yi = y0 + dy; float wy = dy ? fy : 1.f - fy;
                for (int dx = 0; dx < 2; dx++) {
                    int xi = x0 + dx; float wx = dx ? fx : 1.f - fx;
                    if (xi >= 0 && xi < VV && yi >= 0 && yi < VV && zi >= 0 && zi < VV)
                        acc += wx * wy * wz * fc[(zi * VV + yi) * VV + xi];
                }
            }
        }
        fixh[tid] = (_Float16)acc;
    }
    if (tid >= 225 && tid < 228) {
        int k = tid - 225;
        for (int q = PP; q < RP; q++) { rowp2[k][q] = 0.f; poolv2[k][q] = 0.f; }
    }
    __syncthreads();

    if (tid < PP) {
        int p = tid;
        int h_ = p / 15, w_ = p - 15 * h_;
        float A = sv(h_), B = sv(w_);
        half8 f8 = *(const half8*)fixh;
        float a0 = alpha[0], a1 = alpha[1];

        int pu01; float wAu01, wBu01; paxis(gx + B, pu01, wAu01, wBu01);
        int pu2 ; float wAu2 , wBu2 ; paxis(gy + B, pu2 , wAu2 , wBu2 );
        int va0, va1; float wva0, wva1; vaxis(gy + A, va0, va1, wva0, wva1);
        int wa0, wa1; float wwa0, wwa1; vaxis(gz + A, wa0, wa1, wwa0, wwa1);
        int zu0, zu1; float wzu0, wzu1; vaxis(gz, zu0, zu1, wzu0, wzu1);
        int vy0, vy1; float wvy0, wvy1; vaxis(gy, vy0, vy1, wvy0, wvy1);
        int vx0, vx1; float wvx0, wvx1; vaxis(gx, vx0, vx1, wvx0, wvx1);

        float s0 = sample_ssd(volA, pu01, wAu01, wBu01, va0, va1, wva0, wva1, zu0, zu1, wzu0, wzu1, f8);
        float s1 = sample_ssd(volA, pu01, wAu01, wBu01, vy0, vy1, wvy0, wvy1, wa0, wa1, wwa0, wwa1, f8);
        float s2 = sample_ssd(volB, pu2 , wAu2 , wBu2 , vx0, vx1, wvx0, wvx1, wa0, wa1, wwa0, wwa1, f8);
        rowp2[0][p] = a1 + a0 * s0;
        rowp2[1][p] = a1 + a0 * s1;
        rowp2[2][p] = a1 + a0 * s2;
    }
    __syncthreads();

    if (tid < 255) {
        int k = tid / 85, r = tid - 85 * k;
        int a = r / 5, bc = r - 5 * a;
        int b0 = bc * 4;
        int ra = max(a - 2, 0) * 15;
        int rb = min(max(a - 1, 0), 14) * 15;
        int rc = min(a, 14) * 15;
        float cm[6];
#pragma unroll
        for (int j = 0; j < 6; j++) {
            int cj = min(max(b0 - 2 + j, 0), 14);
            float m0 = rowp2[k][ra + cj];
            float m1 = rowp2[k][rb + cj];
            float m2 = rowp2[k][rc + cj];
            cm[j] = fminf(fminf(m0, m1), m2);
        }
#pragma unroll
        for (int o = 0; o < 4; o++) {
            int b = b0 + o;
            if (b < 17) smin[k * 289 + a * 17 + b] = fminf(fminf(cm[o], cm[o + 1]), cm[o + 2]);
        }
    }
    __syncthreads();

    if (tid < 180) {
        int k = tid / 60, r = tid - 60 * k;
        int h = r >> 2, wc = r & 3;
        int w0 = wc * 4;
        const float* S = smin + k * 289;
        float cs[6];
#pragma unroll
        for (int j = 0; j < 6; j++) {
            int cj = min(w0 + j, 16);
            cs[j] = S[h * 17 + cj] + S[(h + 1) * 17 + cj] + S[(h + 2) * 17 + cj];
        }
#pragma unroll
        for (int o = 0; o < 4; o++) {
            int w = w0 + o;
            if (w < 15) poolv2[k][h * 15 + w] = (cs[o] + cs[o + 1] + cs[o + 2]) * (1.f / 9.f);
        }
    }
    __syncthreads();

    if (tid < 169) {
        int c0 = tid * 4;
        half4 hp, hq;
#pragma unroll
        for (int j = 0; j < 4; j++) {
            int i = c0 + j;
            int p = i / 3, k = i - 3 * p;
            hp[j] = (_Float16)rowp2[k][p];
            hq[j] = (_Float16)poolv2[k][p];
        }
        *(half4*)(pdd + (size_t)n * CHP + c0) = hp;
        *(half4*)(pool + (size_t)n * CHP + c0) = hq;
    }
}

// z-axis 5-tap triangle, segmented (round 6, verified).
__global__ __launch_bounds__(256) void gs_z4s(const _Float16* __restrict__ in,
                                              _Float16* __restrict__ out) {
    const int COLS = GS2 * 169;
    int id = blockIdx.x * 256 + threadIdx.x;
    if (id >= COLS) return;
    int seg = blockIdx.y;
    int z0 = seg * 8;
    int z1 = min(z0 + 8, GS);
    int row = id / 169, c4 = id - 169 * row;
    size_t base = (size_t)row * CHP + c4 * 4;
    const size_t ZS = (size_t)GS2 * CHP;
    const float w0 = 1.f / 9.f, w1 = 2.f / 9.f, w2 = 3.f / 9.f;

    float v0[4], v1[4], v2[4], v3[4], v4[4];
    {
        int za = max(z0 - 2, 0), zb = max(z0 - 1, 0);
        int zd = min(z0 + 1, GS - 1), ze = min(z0 + 2, GS - 1);
        half4 ha = *(const half4*)(in + base + (size_t)za * ZS);
        half4 hb = *(const half4*)(in + base + (size_t)zb * ZS);
        half4 hc = *(const half4*)(in + base + (size_t)z0 * ZS);
        half4 hd = *(const half4*)(in + base + (size_t)zd * ZS);
        half4 he = *(const half4*)(in + base + (size_t)ze * ZS);
#pragma unroll
        for (int j = 0; j < 4; j++) {
            v0[j] = (float)ha[j]; v1[j] = (float)hb[j]; v2[j] = (float)hc[j];
            v3[j] = (float)hd[j]; v4[j] = (float)he[j];
        }
    }
    for (int z = z0; z < z1; z++) {
        half4 o;
#pragma unroll
        for (int j = 0; j < 4; j++)
            o[j] = (_Float16)(w0 * (v0[j] + v4[j]) + w1 * (v1[j] + v3[j]) + w2 * v2[j]);
        *(half4*)(out + base + (size_t)z * ZS) = o;
        int zn = min(z + 3, GS - 1);
        half4 hn = *(const half4*)(in + base + (size_t)zn * ZS);
#pragma unroll
        for (int j = 0; j < 4; j++) {
            v0[j] = v1[j]; v1[j] = v2[j]; v2[j] = v3[j]; v3[j] = v4[j];
            v4[j] = (float)hn[j];
        }
    }
}

// Per n (XCD-swizzled): y-smooth + cost + pooling -> pool2.
__global__ __launch_bounds__(256) void cost_pool2_y(const _Float16* __restrict__ zs,
                                                    const _Float16* __restrict__ pdd,
                                                    const float* __restrict__ alpha,
                                                    _Float16* __restrict__ pool2) {
    int n = xcd_swz(blockIdx.x, NCP);
    int tid = threadIdx.x;
    int x = n % GS; int zy = n / GS; int y = zy % GS; int z = zy / GS;
    __shared__ float rowp2[3][RP];
    __shared__ float smin[3 * 289];
    __shared__ float poolv2[3][RP];

    if (tid >= 225 && tid < 228) {
        int k = tid - 225;
        for (int q = PP; q < RP; q++) { rowp2[k][q] = 0.f; poolv2[k][q] = 0.f; }
    }
    if (tid < 169) {
        int c0 = tid * 4;
        float s0 = 0.f, s1 = 0.f, s2 = 0.f, s3 = 0.f;
#pragma unroll
        for (int dy = 0; dy < 5; dy++) {
            int yy = min(max(y + dy - 2, 0), GS - 1);
            size_t off = ((size_t)(z * GS + yy) * GS + x) * CHP + c0;
            float w = (3.f - fabsf((float)dy - 2.f)) * (1.f / 9.f);
            half4 hv = *(const half4*)(zs + off);
            s0 = fmaf(w, (float)hv[0], s0);
            s1 = fmaf(w, (float)hv[1], s1);
            s2 = fmaf(w, (float)hv[2], s2);
            s3 = fmaf(w, (float)hv[3], s3);
        }
        float a2 = alpha[2], a3 = alpha[3], a4 = alpha[4];
        half4 pv = *(const half4*)(pdd + (size_t)n * CHP + c0);
        float sm[4] = {s0, s1, s2, s3};
#pragma unroll
        for (int j = 0; j < 4; j++) {
            int i = c0 + j;
            if (i < CH) {
                int p = i / 3, k = i - 3 * p;
                rowp2[k][p] = a4 + a2 * (float)pv[j] + a3 * sm[j];
            }
        }
    }
    __syncthreads();

    if (tid < 255) {
        int k = tid / 85, r = tid - 85 * k;
        int a = r / 5, bc = r - 5 * a;
        int b0 = bc * 4;
        int ra = max(a - 2, 0) * 15;
        int rb = min(max(a - 1, 0), 14) * 15;
        int rc = min(a, 14) * 15;
        float cm[6];
#pragma unroll
        for (int j = 0; j < 6; j++) {
            int cj = min(max(b0 - 2 + j, 0), 14);
            float m0 = rowp2[k][ra + cj];
            float m1 = rowp2[k][rb + cj];
            float m2 = rowp2[k][rc + cj];
            cm[j] = fminf(fminf(m0, m1), m2);
        }
#pragma unroll
        for (int o = 0; o < 4; o++) {
            int b = b0 + o;
            if (b < 17) smin[k * 289 + a * 17 + b] = fminf(fminf(cm[o], cm[o + 1]), cm[o + 2]);
        }
    }
    __syncthreads();

    if (tid < 180) {
        int k = tid / 60, r = tid - 60 * k;
        int h = r >> 2, wc = r & 3;
        int w0 = wc * 4;
        const float* S = smin + k * 289;
        float cs[6];
#pragma unroll
        for (int j = 0; j < 6; j++) {
            int cj = min(w0 + j, 16);
            cs[j] = S[h * 17 + cj] + S[(h + 1) * 17 + cj] + S[(h + 2) * 17 + cj];
        }
#pragma unroll
        for (int o = 0; o < 4; o++) {
            int w = w0 + o;
            if (w < 15) poolv2[k][h * 15 + w] = (cs[o] + cs[o + 1] + cs[o + 2]) * (1.f / 9.f);
        }
    }
    __syncthreads();

    if (tid < 169) {
        int c0 = tid * 4;
        half4 hq;
#pragma unroll
        for (int j = 0; j < 4; j++) {
            int i = c0 + j;
            int p = i / 3, k = i - 3 * p;
            hq[j] = (_Float16)poolv2[k][p];
        }
        *(half4*)(pool2 + (size_t)n * CHP + c0) = hq;
    }
}

// Per n (XCD-swizzled): y-smooth -> cost_avg; softmax + pred from LDS.
__global__ __launch_bounds__(256) void smooth_y_softmax(const _Float16* __restrict__ zs,
                                                        const float* __restrict__ alpha,
                                                        float* __restrict__ ca,
                                                        float* __restrict__ soft,
                                                        float* __restrict__ pred) {
    int n = xcd_swz(blockIdx.x, NCP);
    int tid = threadIdx.x;
    int x = n % GS; int zy = n / GS; int y = zy % GS; int z = zy / GS;
    int wave = tid >> 6, lane = tid & 63;
    __shared__ float vals[CHP];
    __shared__ float partial[3][3];

    if (tid < 169) {
        int c0 = tid * 4;
        float s0 = 0.f, s1 = 0.f, s2 = 0.f, s3 = 0.f;
#pragma unroll
        for (int dy = 0; dy < 5; dy++) {
            int yy = min(max(y + dy - 2, 0), GS - 1);
            size_t off = ((size_t)(z * GS + yy) * GS + x) * CHP + c0;
            float w = (3.f - fabsf((float)dy - 2.f)) * (1.f / 9.f);
            half4 hv = *(const half4*)(zs + off);
            s0 = fmaf(w, (float)hv[0], s0);
            s1 = fmaf(w, (float)hv[1], s1);
            s2 = fmaf(w, (float)hv[2], s2);
            s3 = fmaf(w, (float)hv[3], s3);
        }
        vals[c0 + 0] = s0;
        vals[c0 + 1] = s1;
        vals[c0 + 2] = s2;
        vals[c0 + 3] = s3;
    }
    __syncthreads();

    for (int i = tid; i < CH; i += 256) ca[(size_t)n * CH + i] = vals[i];
    __syncthreads();

    float a5 = alpha[5];
    if (wave < 3) {
        int k = wave;
        float v[4], e[4];
        float m = -1e30f;
#pragma unroll
        for (int j = 0; j < 4; j++) {
            int p = lane + 64 * j;
            v[j] = (p < PP) ? -a5 * vals[p * 3 + k] : -1e30f;
            m = fmaxf(m, v[j]);
        }
#pragma unroll
        for (int o = 32; o > 0; o >>= 1) m = fmaxf(m, __shfl_xor(m, o));
        float sum = 0.f;
#pragma unroll
        for (int j = 0; j < 4; j++) {
            int p = lane + 64 * j;
            e[j] = (p < PP) ? __expf(v[j] - m) : 0.f;
            sum += e[j];
        }
#pragma unroll
        for (int o = 32; o > 0; o >>= 1) sum += __shfl_xor(sum, o);
        float inv = 1.f / sum;
        float px = 0.f, py = 0.f, pz = 0.f;
#pragma unroll
        for (int j = 0; j < 4; j++) {
            int p = lane + 64 * j;
            if (p < PP) {
                float s = e[j] * inv;
                vals[p * 3 + k] = s;
                int h_ = p / 15, w_ = p - 15 * h_;
                float A = sv(h_), B = sv(w_);
                if (k == 0)      { px += s * B; py += s * A; }
                else if (k == 1) { px += s * B; pz += s * A; }
                else             { py += s * B; pz += s * A; }
            }
        }
#pragma unroll
        for (int o = 32; o > 0; o >>= 1) {
            px += __shfl_xor(px, o);
            py += __shfl_xor(py, o);
            pz += __shfl_xor(pz, o);
        }
        if (lane == 0) { partial[k][0] = px; partial[k][1] = py; partial[k][2] = pz; }
    }
    __syncthreads();
    if (tid < 3) pred[(size_t)n * 3 + tid] = 0.5f * (partial[0][tid] + partial[1][tid] + partial[2][tid]);
    for (int i = tid; i < CH; i += 256) soft[(size_t)n * CH + i] = vals[i];
}

extern "C" void kernel_launch(void* const* d_in, const int* in_sizes, int n_in,
                              void* d_out, int out_size, void* d_ws, size_t ws_size,
                              hipStream_t stream) {
    const float* f00   = (const float*)d_in[0];
    const float* f50   = (const float*)d_in[1];
    const float* grid  = (const float*)d_in[3];
    const float* alpha = (const float*)d_in[5];

    float* out0 = (float*)d_out;                   // cost_soft  (N*675)
    float* out1 = out0 + (size_t)NCP * CH;         // pred_xyz   (N*3)
    float* out2 = out1 + (size_t)NCP * 3;          // cost_avg   (N*675)

    char* ws = (char*)d_ws;
    _Float16* volA = (_Float16*)ws;                          // 4MB
    _Float16* volB = volA + (size_t)V3 * 8;                  // 4MB
    _Float16* H0 = volB + (size_t)V3 * 8;                    // N*CHP fp16 (pdd)
    _Float16* H1 = H0 + (size_t)NCP * CHP;                   // N*CHP fp16 (pool1 -> pool2)
    _Float16* H2 = H1 + (size_t)NCP * CHP;                   // N*CHP fp16 (z-smooth tmp)

    make_vols<<<(V3 + 255) / 256, 256, 0, stream>>>(f50, volA, volB);

    pdd_pool_n<<<NCP, 256, 0, stream>>>(f00, volA, volB, grid, alpha, H0, H1);

    const int COLS = GS2 * 169;
    const int gbz = (COLS + 255) / 256;
    dim3 gz(gbz, 4);

    gs_z4s<<<gz, 256, 0, stream>>>(H1, H2);
    cost_pool2_y<<<NCP, 256, 0, stream>>>(H2, H0, alpha, H1);

    gs_z4s<<<gz, 256, 0, stream>>>(H1, H2);
    smooth_y_softmax<<<NCP, 256, 0, stream>>>(H2, alpha, out2, out0, out1);
}